// Round 3
// baseline (254.244 us; speedup 1.0000x reference)
//
#include <hip/hip_runtime.h>
#include <math.h>

// PANLoss: dice(regions) + 0.5*dice(kernels) + 0.25*(agg + dis)
//
// R11 = R10 + residency-tail fix.
//
// R10 post-mortem: pan_main ~51us (fell out of top-5; harness fills at
// 61us/6.9TB/s now dominate the dispatch list). Memory floor = 262MB /
// 6.9TB/s ~= 38-42us. The ~20% gap matches a residency tail: grid is
// 1280 blocks = exactly 5 blocks/CU, but VGPR in the 103..128 band
// gives only 4 waves/SIMD -> 4 blocks/CU resident -> each CU runs a
// straggler 5th block at 1-block occupancy (~+20%).
//
// Fixes: (a) __launch_bounds__(256,5) caps VGPR at 102 so 5 blocks/CU
// co-reside (zero tail); (b) all index math in 32-bit (max byte offset
// = sim's 105MB < 2^31) to cut address VGPRs/carry chains and make the
// 102 cap comfortable.
//
// ws per batch (NACC=51 floats, slots 0,9,18,27,36 unused/zero):
//   [1..8] ct  [10..17] ck  [19..26] St  [28..35] Sk  [37..44] Ss
//   [45..47] regions pg/pp/gg   [48..50] kernels pg/pp/gg

#define NSEG 9
#define NACC 51
#define NBATCH 16
#define EPSF 1e-5f
#define G 5          // float4 groups per thread
#define BPB 80       // blocks per batch: 102400 float4 / (256*G) = 80 exact

typedef float  vfloat4 __attribute__((ext_vector_type(4)));
typedef int    vint4   __attribute__((ext_vector_type(4)));

__device__ __forceinline__ float wave_reduce_sum(float v) {
#pragma unroll
    for (int off = 32; off > 0; off >>= 1)
        v += __shfl_down(v, off, 64);
    return v;
}

__device__ __forceinline__ float sigm(float x) {
    return 1.0f / (1.0f + __expf(-x));
}

__device__ __forceinline__ vfloat4 nt_load4(const float* p) {
    return __builtin_nontemporal_load((const vfloat4*)p);
}
__device__ __forceinline__ vint4 nt_load4i(const int* p) {
    return __builtin_nontemporal_load((const vint4*)p);
}

__global__ __launch_bounds__(256, 5) void pan_main(
    const float* __restrict__ pred_r, const float* __restrict__ gt_r,
    const float* __restrict__ pred_k, const float* __restrict__ gt_k,
    const float* __restrict__ sim,
    const int* __restrict__ tlab, const int* __restrict__ klab,
    float* __restrict__ ws, int npix)
{
    const int tid = threadIdx.x;
    const int b = blockIdx.y;
    const int base = b * npix;                 // <= 6.55M, fits int
    const int sbase = b * 4 * npix;            // <= 26.2M, fits int
    const int i0 = blockIdx.x * (256 * G) + tid;  // float4 index of group 0

    float St_[8], Sk_[8], Ss_[8];
    unsigned ct_[8], ck_[8];
#pragma unroll
    for (int s = 0; s < 8; ++s) {
        St_[s] = 0.0f; Sk_[s] = 0.0f; Ss_[s] = 0.0f;
        ct_[s] = 0u; ck_[s] = 0u;
    }
    float rpg = 0.0f, rpp = 0.0f, rgg = 0.0f;
    float kpg = 0.0f, kpp = 0.0f, kgg = 0.0f;

#pragma unroll 1
    for (int g = 0; g < G; ++g) {
        const int e = (i0 + g * 256) * 4;      // element offset, <= 1.64M

        // ---- 10 independent NT loads ----
        const vfloat4 pr = nt_load4(pred_r + base + e);
        const vfloat4 gr = nt_load4(gt_r + base + e);
        const vfloat4 pk = nt_load4(pred_k + base + e);
        const vfloat4 gk = nt_load4(gt_k + base + e);
        const vfloat4 c0 = nt_load4(sim + sbase + e);
        const vfloat4 c1 = nt_load4(sim + sbase + npix + e);
        const vfloat4 c2 = nt_load4(sim + sbase + 2 * npix + e);
        const vfloat4 c3 = nt_load4(sim + sbase + 3 * npix + e);
        const vint4 tl = nt_load4i(tlab + base + e);
        const vint4 kl = nt_load4i(klab + base + e);

        // ---- dice sums (g in {0,1} so g*g == g) ----
        {
            float p;
            p = sigm(pr.x); rpg += p * gr.x; rpp += p * p; rgg += gr.x;
            p = sigm(pr.y); rpg += p * gr.y; rpp += p * p; rgg += gr.y;
            p = sigm(pr.z); rpg += p * gr.z; rpp += p * p; rgg += gr.z;
            p = sigm(pr.w); rpg += p * gr.w; rpp += p * p; rgg += gr.w;
            p = sigm(pk.x); kpg += p * gk.x; kpp += p * p; kgg += gk.x;
            p = sigm(pk.y); kpg += p * gk.y; kpp += p * p; kgg += gk.y;
            p = sigm(pk.z); kpg += p * gk.z; kpp += p * p; kgg += gk.z;
            p = sigm(pk.w); kpg += p * gk.w; kpp += p * p; kgg += gk.w;
        }

        const float s2x = c0.x * c0.x + c1.x * c1.x + c2.x * c2.x + c3.x * c3.x;
        const float s2y = c0.y * c0.y + c1.y * c1.y + c2.y * c2.y + c3.y * c3.y;
        const float s2z = c0.z * c0.z + c1.z * c1.z + c2.z * c2.z + c3.z * c3.z;
        const float s2w = c0.w * c0.w + c1.w * c1.w + c2.w * c2.w + c3.w * c3.w;

#define DO_COMP(TL, KL, S2)                                      \
        {                                                        \
            bool tt = ((TL) == s);                               \
            bool kk = ((KL) == s);                               \
            ct_[s - 1] += (unsigned)__popcll(__ballot(tt));      \
            ck_[s - 1] += (unsigned)__popcll(__ballot(kk));      \
            St_[s - 1] += tt ? (S2) : 0.0f;                      \
            Sk_[s - 1] += kk ? (S2) : 0.0f;                      \
            Ss_[s - 1] += (tt && kk) ? (S2) : 0.0f;              \
        }

#pragma unroll
        for (int s = 1; s <= 8; ++s) {
            DO_COMP(tl.x, kl.x, s2x);
            DO_COMP(tl.y, kl.y, s2y);
            DO_COMP(tl.z, kl.z, s2z);
            DO_COMP(tl.w, kl.w, s2w);
        }
#undef DO_COMP
    }

    // ---- block reduction: wave shuffle -> LDS -> one atomicAdd per qty ----
    __shared__ float red[4][NACC];
    const int lane = tid & 63;
    const int wv = tid >> 6;

#pragma unroll
    for (int s = 0; s < 8; ++s) {
        float v;
        v = wave_reduce_sum(St_[s]); if (lane == 0) red[wv][19 + s] = v;
        v = wave_reduce_sum(Sk_[s]); if (lane == 0) red[wv][28 + s] = v;
        v = wave_reduce_sum(Ss_[s]); if (lane == 0) red[wv][37 + s] = v;
    }
    {
        float v;
        v = wave_reduce_sum(rpg); if (lane == 0) red[wv][45] = v;
        v = wave_reduce_sum(rpp); if (lane == 0) red[wv][46] = v;
        v = wave_reduce_sum(rgg); if (lane == 0) red[wv][47] = v;
        v = wave_reduce_sum(kpg); if (lane == 0) red[wv][48] = v;
        v = wave_reduce_sum(kpp); if (lane == 0) red[wv][49] = v;
        v = wave_reduce_sum(kgg); if (lane == 0) red[wv][50] = v;
    }
    if (lane == 0) {
        // ballot counts are wave-uniform
#pragma unroll
        for (int s = 0; s < 8; ++s) {
            red[wv][1 + s] = (float)ct_[s];
            red[wv][10 + s] = (float)ck_[s];
        }
        red[wv][0] = 0.0f; red[wv][9] = 0.0f; red[wv][18] = 0.0f;
        red[wv][27] = 0.0f; red[wv][36] = 0.0f;
    }
    __syncthreads();
    if (tid < NACC) {
        float s = red[0][tid] + red[1][tid] + red[2][tid] + red[3][tid];
        atomicAdd(&ws[b * NACC + tid], s);
    }
}

__global__ __launch_bounds__(64) void pan_finalize(
    const float* __restrict__ ws, float* __restrict__ out)
{
    const int b = threadIdx.x;
    float dice_r = 0.0f, dice_k = 0.0f, lagg = 0.0f, ldis = 0.0f;

    if (b < NBATCH) {
        const float* w = ws + b * NACC;
        {
            float pg = w[45], pp = w[46], gg = w[47];
            dice_r = 1.0f - (2.0f * pg + EPSF) / ((pp + EPSF) + (gg + EPSF));
            pg = w[48]; pp = w[49]; gg = w[50];
            dice_k = 1.0f - (2.0f * pg + EPSF) / ((pp + EPSF) + (gg + EPSF));
        }
        float a[8];
#pragma unroll
        for (int i = 1; i < NSEG; ++i) {
            float ct = w[i], ck = w[NSEG + i];
            float St = w[2 * NSEG + i], Sk = w[3 * NSEG + i], Ss = w[4 * NSEG + i];
            float inv = 1.0f / (ck + 1.0f);
            float omi = 1.0f - inv;
            float n2 = omi * omi * Ss + (St - Ss) + inv * inv * (Sk - Ss);
            float nrm = sqrtf(n2);
            float d = nrm - 0.5f;  // SIGMA_AGG (no clamp — matches reference)
            lagg += logf(d * d + 1.0f) / (ct + 1.0f);
            float ckd = ck + 0.001f;
            a[i - 1] = Sk / (ckd * ckd);
        }
#pragma unroll
        for (int i = 0; i < 8; ++i) {
#pragma unroll
            for (int j = i + 1; j < 8; ++j) {
                float pair = 3.0f - sqrtf(a[i] + a[j]);  // SIGMA_DIS
                ldis += logf(pair * pair + 1.0f);
            }
        }
        ldis *= (1.0f / 56.0f);  // K_MAX*(K_MAX-1)
    }

    dice_r = wave_reduce_sum(dice_r);
    dice_k = wave_reduce_sum(dice_k);
    lagg = wave_reduce_sum(lagg);
    ldis = wave_reduce_sum(ldis);

    if (threadIdx.x == 0) {
        float loss = dice_r + 0.5f * dice_k + 0.25f * (lagg + ldis);
        out[0] = loss;
        out[1] = dice_r;
        out[2] = dice_k;
        out[3] = lagg;
        out[4] = ldis;
    }
}

extern "C" void kernel_launch(void* const* d_in, const int* in_sizes, int n_in,
                              void* d_out, int out_size, void* d_ws, size_t ws_size,
                              hipStream_t stream) {
    const float* pred_r = (const float*)d_in[0];
    const float* gt_r   = (const float*)d_in[1];
    const float* pred_k = (const float*)d_in[2];
    const float* gt_k   = (const float*)d_in[3];
    const float* sim    = (const float*)d_in[4];
    const int*   tlab   = (const int*)d_in[5];
    const int*   klab   = (const int*)d_in[6];
    float* out = (float*)d_out;
    float* ws  = (float*)d_ws;

    const int npix = in_sizes[0] / NBATCH;  // 640*640 = 409600

    (void)hipMemsetAsync(ws, 0, NBATCH * NACC * sizeof(float), stream);

    dim3 grid(BPB, NBATCH);
    pan_main<<<grid, 256, 0, stream>>>(pred_r, gt_r, pred_k, gt_k, sim,
                                       tlab, klab, ws, npix);
    pan_finalize<<<1, 64, 0, stream>>>(ws, out);
}

// Round 4
// 252.007 us; speedup vs baseline: 1.0089x; 1.0089x over previous
//
#include <hip/hip_runtime.h>
#include <math.h>

// PANLoss: dice(regions) + 0.5*dice(kernels) + 0.25*(agg + dis)
//
// R12 = R11 + stream phase-decorrelation.
//
// R11 post-mortem: launch_bounds(256,5)+32-bit addressing = neutral ->
// occupancy/residency exonerated. VALU (~9-18us under 38us floor with
// 5-wave TLP), MLP (200KB/CU outstanding >> 22KB needed), and every
// individual pipe (HBM 2.6/6.9, L2 5.1/34.5) are all underloaded, yet
// delivered BW pins at ~5.1 TB/s vs the 6.9 TB/s the harness's own
// fills prove. Remaining suspect: 26 concurrent streams phase-LOCKED
// at an exact 25 MiB stride (every thread reads the same pixel offset
// of every array) -> all streams hit the same HBM channel phase at
// every instant, sweeping in lockstep = channel hotspotting.
//
// Fix: dice(regions), dice(kernels), and the tree are pixel-independent
// reductions, so rotate each group's block index separately:
//   group C (sim x4 + tlab + klab): bx + 5*b          (batch stagger)
//   group A (pred_r + gt_r):        bx + 5*b + 27
//   group B (pred_k + gt_k):        bx + 5*b + 53
// (mod 80 = bijection -> exact coverage; coalescing unchanged; ~6 SALU
// per block.) Intra-group phase lock (sim channels + labels) is
// algorithmically unavoidable.
//
// ws per batch (NACC=51 floats, slots 0,9,18,27,36 unused/zero):
//   [1..8] ct  [10..17] ck  [19..26] St  [28..35] Sk  [37..44] Ss
//   [45..47] regions pg/pp/gg   [48..50] kernels pg/pp/gg

#define NSEG 9
#define NACC 51
#define NBATCH 16
#define EPSF 1e-5f
#define G 5          // float4 groups per thread
#define BPB 80       // blocks per batch: 102400 float4 / (256*G) = 80 exact

typedef float  vfloat4 __attribute__((ext_vector_type(4)));
typedef int    vint4   __attribute__((ext_vector_type(4)));

__device__ __forceinline__ float wave_reduce_sum(float v) {
#pragma unroll
    for (int off = 32; off > 0; off >>= 1)
        v += __shfl_down(v, off, 64);
    return v;
}

__device__ __forceinline__ float sigm(float x) {
    return 1.0f / (1.0f + __expf(-x));
}

__device__ __forceinline__ vfloat4 nt_load4(const float* p) {
    return __builtin_nontemporal_load((const vfloat4*)p);
}
__device__ __forceinline__ vint4 nt_load4i(const int* p) {
    return __builtin_nontemporal_load((const vint4*)p);
}

__global__ __launch_bounds__(256, 5) void pan_main(
    const float* __restrict__ pred_r, const float* __restrict__ gt_r,
    const float* __restrict__ pred_k, const float* __restrict__ gt_k,
    const float* __restrict__ sim,
    const int* __restrict__ tlab, const int* __restrict__ klab,
    float* __restrict__ ws, int npix)
{
    const int tid = threadIdx.x;
    const int b = blockIdx.y;
    const int base = b * npix;                 // <= 6.55M, fits int
    const int sbase = b * 4 * npix;            // <= 26.2M, fits int

    // phase-decorrelated block indices (all mod BPB, bijective)
    int bxC = blockIdx.x + 5 * b;            // tree: sim + labels
    if (bxC >= BPB) bxC -= BPB;
    int bxA = bxC + 27;                      // regions dice
    if (bxA >= BPB) bxA -= BPB;
    int bxB = bxC + 53;                      // kernels dice
    if (bxB >= BPB) bxB -= BPB;

    const int i0C = bxC * (256 * G) + tid;   // float4 index, group 0
    const int i0A = bxA * (256 * G) + tid;
    const int i0B = bxB * (256 * G) + tid;

    float St_[8], Sk_[8], Ss_[8];
    unsigned ct_[8], ck_[8];
#pragma unroll
    for (int s = 0; s < 8; ++s) {
        St_[s] = 0.0f; Sk_[s] = 0.0f; Ss_[s] = 0.0f;
        ct_[s] = 0u; ck_[s] = 0u;
    }
    float rpg = 0.0f, rpp = 0.0f, rgg = 0.0f;
    float kpg = 0.0f, kpp = 0.0f, kgg = 0.0f;

#pragma unroll 1
    for (int g = 0; g < G; ++g) {
        const int eC = (i0C + g * 256) * 4;  // element offsets
        const int eA = (i0A + g * 256) * 4;
        const int eB = (i0B + g * 256) * 4;

        // ---- 10 independent NT loads ----
        const vfloat4 pr = nt_load4(pred_r + base + eA);
        const vfloat4 gr = nt_load4(gt_r + base + eA);
        const vfloat4 pk = nt_load4(pred_k + base + eB);
        const vfloat4 gk = nt_load4(gt_k + base + eB);
        const vfloat4 c0 = nt_load4(sim + sbase + eC);
        const vfloat4 c1 = nt_load4(sim + sbase + npix + eC);
        const vfloat4 c2 = nt_load4(sim + sbase + 2 * npix + eC);
        const vfloat4 c3 = nt_load4(sim + sbase + 3 * npix + eC);
        const vint4 tl = nt_load4i(tlab + base + eC);
        const vint4 kl = nt_load4i(klab + base + eC);

        // ---- dice sums (g in {0,1} so g*g == g) ----
        {
            float p;
            p = sigm(pr.x); rpg += p * gr.x; rpp += p * p; rgg += gr.x;
            p = sigm(pr.y); rpg += p * gr.y; rpp += p * p; rgg += gr.y;
            p = sigm(pr.z); rpg += p * gr.z; rpp += p * p; rgg += gr.z;
            p = sigm(pr.w); rpg += p * gr.w; rpp += p * p; rgg += gr.w;
            p = sigm(pk.x); kpg += p * gk.x; kpp += p * p; kgg += gk.x;
            p = sigm(pk.y); kpg += p * gk.y; kpp += p * p; kgg += gk.y;
            p = sigm(pk.z); kpg += p * gk.z; kpp += p * p; kgg += gk.z;
            p = sigm(pk.w); kpg += p * gk.w; kpp += p * p; kgg += gk.w;
        }

        const float s2x = c0.x * c0.x + c1.x * c1.x + c2.x * c2.x + c3.x * c3.x;
        const float s2y = c0.y * c0.y + c1.y * c1.y + c2.y * c2.y + c3.y * c3.y;
        const float s2z = c0.z * c0.z + c1.z * c1.z + c2.z * c2.z + c3.z * c3.z;
        const float s2w = c0.w * c0.w + c1.w * c1.w + c2.w * c2.w + c3.w * c3.w;

#define DO_COMP(TL, KL, S2)                                      \
        {                                                        \
            bool tt = ((TL) == s);                               \
            bool kk = ((KL) == s);                               \
            ct_[s - 1] += (unsigned)__popcll(__ballot(tt));      \
            ck_[s - 1] += (unsigned)__popcll(__ballot(kk));      \
            St_[s - 1] += tt ? (S2) : 0.0f;                      \
            Sk_[s - 1] += kk ? (S2) : 0.0f;                      \
            Ss_[s - 1] += (tt && kk) ? (S2) : 0.0f;              \
        }

#pragma unroll
        for (int s = 1; s <= 8; ++s) {
            DO_COMP(tl.x, kl.x, s2x);
            DO_COMP(tl.y, kl.y, s2y);
            DO_COMP(tl.z, kl.z, s2z);
            DO_COMP(tl.w, kl.w, s2w);
        }
#undef DO_COMP
    }

    // ---- block reduction: wave shuffle -> LDS -> one atomicAdd per qty ----
    __shared__ float red[4][NACC];
    const int lane = tid & 63;
    const int wv = tid >> 6;

#pragma unroll
    for (int s = 0; s < 8; ++s) {
        float v;
        v = wave_reduce_sum(St_[s]); if (lane == 0) red[wv][19 + s] = v;
        v = wave_reduce_sum(Sk_[s]); if (lane == 0) red[wv][28 + s] = v;
        v = wave_reduce_sum(Ss_[s]); if (lane == 0) red[wv][37 + s] = v;
    }
    {
        float v;
        v = wave_reduce_sum(rpg); if (lane == 0) red[wv][45] = v;
        v = wave_reduce_sum(rpp); if (lane == 0) red[wv][46] = v;
        v = wave_reduce_sum(rgg); if (lane == 0) red[wv][47] = v;
        v = wave_reduce_sum(kpg); if (lane == 0) red[wv][48] = v;
        v = wave_reduce_sum(kpp); if (lane == 0) red[wv][49] = v;
        v = wave_reduce_sum(kgg); if (lane == 0) red[wv][50] = v;
    }
    if (lane == 0) {
        // ballot counts are wave-uniform
#pragma unroll
        for (int s = 0; s < 8; ++s) {
            red[wv][1 + s] = (float)ct_[s];
            red[wv][10 + s] = (float)ck_[s];
        }
        red[wv][0] = 0.0f; red[wv][9] = 0.0f; red[wv][18] = 0.0f;
        red[wv][27] = 0.0f; red[wv][36] = 0.0f;
    }
    __syncthreads();
    if (tid < NACC) {
        float s = red[0][tid] + red[1][tid] + red[2][tid] + red[3][tid];
        atomicAdd(&ws[b * NACC + tid], s);
    }
}

__global__ __launch_bounds__(64) void pan_finalize(
    const float* __restrict__ ws, float* __restrict__ out)
{
    const int b = threadIdx.x;
    float dice_r = 0.0f, dice_k = 0.0f, lagg = 0.0f, ldis = 0.0f;

    if (b < NBATCH) {
        const float* w = ws + b * NACC;
        {
            float pg = w[45], pp = w[46], gg = w[47];
            dice_r = 1.0f - (2.0f * pg + EPSF) / ((pp + EPSF) + (gg + EPSF));
            pg = w[48]; pp = w[49]; gg = w[50];
            dice_k = 1.0f - (2.0f * pg + EPSF) / ((pp + EPSF) + (gg + EPSF));
        }
        float a[8];
#pragma unroll
        for (int i = 1; i < NSEG; ++i) {
            float ct = w[i], ck = w[NSEG + i];
            float St = w[2 * NSEG + i], Sk = w[3 * NSEG + i], Ss = w[4 * NSEG + i];
            float inv = 1.0f / (ck + 1.0f);
            float omi = 1.0f - inv;
            float n2 = omi * omi * Ss + (St - Ss) + inv * inv * (Sk - Ss);
            float nrm = sqrtf(n2);
            float d = nrm - 0.5f;  // SIGMA_AGG (no clamp — matches reference)
            lagg += logf(d * d + 1.0f) / (ct + 1.0f);
            float ckd = ck + 0.001f;
            a[i - 1] = Sk / (ckd * ckd);
        }
#pragma unroll
        for (int i = 0; i < 8; ++i) {
#pragma unroll
            for (int j = i + 1; j < 8; ++j) {
                float pair = 3.0f - sqrtf(a[i] + a[j]);  // SIGMA_DIS
                ldis += logf(pair * pair + 1.0f);
            }
        }
        ldis *= (1.0f / 56.0f);  // K_MAX*(K_MAX-1)
    }

    dice_r = wave_reduce_sum(dice_r);
    dice_k = wave_reduce_sum(dice_k);
    lagg = wave_reduce_sum(lagg);
    ldis = wave_reduce_sum(ldis);

    if (threadIdx.x == 0) {
        float loss = dice_r + 0.5f * dice_k + 0.25f * (lagg + ldis);
        out[0] = loss;
        out[1] = dice_r;
        out[2] = dice_k;
        out[3] = lagg;
        out[4] = ldis;
    }
}

extern "C" void kernel_launch(void* const* d_in, const int* in_sizes, int n_in,
                              void* d_out, int out_size, void* d_ws, size_t ws_size,
                              hipStream_t stream) {
    const float* pred_r = (const float*)d_in[0];
    const float* gt_r   = (const float*)d_in[1];
    const float* pred_k = (const float*)d_in[2];
    const float* gt_k   = (const float*)d_in[3];
    const float* sim    = (const float*)d_in[4];
    const int*   tlab   = (const int*)d_in[5];
    const int*   klab   = (const int*)d_in[6];
    float* out = (float*)d_out;
    float* ws  = (float*)d_ws;

    const int npix = in_sizes[0] / NBATCH;  // 640*640 = 409600

    (void)hipMemsetAsync(ws, 0, NBATCH * NACC * sizeof(float), stream);

    dim3 grid(BPB, NBATCH);
    pan_main<<<grid, 256, 0, stream>>>(pred_r, gt_r, pred_k, gt_k, sim,
                                       tlab, klab, ws, npix);
    pan_finalize<<<1, 64, 0, stream>>>(ws, out);
}